// Round 2
// baseline (1250.940 us; speedup 1.0000x reference)
//
#include <hip/hip_runtime.h>

typedef _Float16 half8 __attribute__((ext_vector_type(8)));
typedef float f32x4 __attribute__((ext_vector_type(4)));
typedef float f32x16 __attribute__((ext_vector_type(16)));

#define DIM 256
#define NE 1024
#define NROWS 131072
#define DECAY 0.99f
#define ONE_MINUS 0.01f
#define EPS 1e-5f

// output offsets (floats) in d_out, concatenated in reference return order
#define OFF_Q    0u
#define OFF_DIFF 33554432u
#define OFF_IND  33554433u
#define OFF_NEMB 33685505u
#define OFF_NCS  33947649u
#define OFF_NEA  33948673u

#define GLOAD16(gp, lp) __builtin_amdgcn_global_load_lds( \
    (__attribute__((address_space(1))) const void*)(gp),  \
    (__attribute__((address_space(3))) void*)(lp), 16, 0, 0)

// ---------------- K0: codebook prep ----------------
// embed [256][1024] fp32 -> bt_hi/bt_lo [1024][256] f16 hi/lo planes (linear,
// swizzle is applied at stage time via source address), embT [1024][256] fp32,
// sqh [1024] = 0.5*||e_j||^2
__global__ void k0_prep(const float* __restrict__ embed,
                        _Float16* __restrict__ bt_hi, _Float16* __restrict__ bt_lo,
                        float* __restrict__ embT, float* __restrict__ sqh) {
    int j = blockIdx.x;        // 0..1023
    int d = threadIdx.x;       // 0..255
    float e = embed[d * NE + j];
    embT[j * DIM + d] = e;
    _Float16 h = (_Float16)e;
    _Float16 lo = (_Float16)(e - (float)h);
    bt_hi[j * DIM + d] = h;
    bt_lo[j * DIM + d] = lo;
    float s = e * e;
    for (int off = 32; off; off >>= 1) s += __shfl_down(s, off);
    __shared__ float wsum[4];
    if ((threadIdx.x & 63) == 0) wsum[threadIdx.x >> 6] = s;
    __syncthreads();
    if (threadIdx.x == 0) sqh[j] = 0.5f * (wsum[0] + wsum[1] + wsum[2] + wsum[3]);
}

// ---------------- K1: distance GEMM (32x32x16) + argmin + quantize + diff + hist ----
// 256 threads = 4 waves; wave owns 32 rows (A hi/lo resident in 128 VGPRs);
// chunk = 32 codes staged hi+lo in LDS (32KB) double-buffered via global_load_lds
// with pre-swizzled source (LDS slot g' holds global granule g = g' ^ (row&7)).
__launch_bounds__(256, 2)
__global__ void k1_main(const float* __restrict__ input,
                        const _Float16* __restrict__ bt_hi,
                        const _Float16* __restrict__ bt_lo,
                        const float* __restrict__ embT,
                        const float* __restrict__ sqh,
                        float* __restrict__ out,
                        int* __restrict__ jint,
                        int* __restrict__ counts,
                        float* __restrict__ diffpart) {
    __shared__ _Float16 Bbuf[2][2][32][256];   // [buf][plane][row][half]  64 KB
    __shared__ float dred[4];

    const int tid = threadIdx.x;
    const int w  = tid >> 6;       // wave 0..3
    const int l  = tid & 63;       // lane
    const int cl = l & 31;         // code column / A row within wave tile
    const int h  = l >> 5;         // k-half
    const int sw = (l & 7) ^ h;    // read-swizzle term
    const int row0 = blockIdx.x * 128 + w * 32;
    const int myrow = row0 + cl;

    // ---- stage chunk 0 (async, in flight during A prep) ----
    {
        #pragma unroll
        for (int i = 0; i < 8; ++i) {
            int q = i * 4 + w;          // 0..31 (wave-uniform)
            int plane = q >> 4;
            int p = q & 15;
            int G = p * 64 + l;
            int r = G >> 5;             // row 0..31
            int g = (G & 31) ^ (r & 7); // source granule (inverse swizzle)
            const _Float16* src = (plane ? bt_lo : bt_hi) + (size_t)r * DIM + g * 8;
            GLOAD16(src, &Bbuf[0][plane][p * 2][0]);
        }
    }

    // ---- A load (one row per lane, 128 dims: ks*16 + h*8 + 0..7) + f16 hi/lo split ----
    half8 ah[16], al[16];
    {
        const float* arow = input + (size_t)myrow * DIM + h * 8;
        #pragma unroll 4
        for (int ks = 0; ks < 16; ++ks) {
            f32x4 x0 = *(const f32x4*)(arow + ks * 16);
            f32x4 x1 = *(const f32x4*)(arow + ks * 16 + 4);
            half8 hh, ll;
            #pragma unroll
            for (int i = 0; i < 4; ++i) {
                _Float16 h0 = (_Float16)x0[i];
                hh[i] = h0; ll[i] = (_Float16)(x0[i] - (float)h0);
                _Float16 h1 = (_Float16)x1[i];
                hh[4 + i] = h1; ll[4 + i] = (_Float16)(x1[i] - (float)h1);
            }
            ah[ks] = hh; al[ks] = ll;
        }
    }

    float best_val[16];
    int   best_idx[16];
    #pragma unroll
    for (int e = 0; e < 16; ++e) { best_val[e] = 3.4e38f; best_idx[e] = 0; }

    __syncthreads();   // drains vmcnt: chunk-0 stage + A loads complete

    int buf = 0;
    #pragma unroll 1
    for (int c = 0; c < 32; ++c) {
        // stage next chunk into the other buffer (latency hidden under MFMA)
        if (c < 31) {
            const int n0n = (c + 1) * 32;
            #pragma unroll
            for (int i = 0; i < 8; ++i) {
                int q = i * 4 + w;
                int plane = q >> 4;
                int p = q & 15;
                int G = p * 64 + l;
                int r = G >> 5;
                int g = (G & 31) ^ (r & 7);
                const _Float16* src = (plane ? bt_lo : bt_hi) + (size_t)(n0n + r) * DIM + g * 8;
                GLOAD16(src, &Bbuf[buf ^ 1][plane][p * 2][0]);
            }
        }
        float sq = sqh[c * 32 + cl];

        f32x16 acc;
        #pragma unroll
        for (int e = 0; e < 16; ++e) acc[e] = 0.f;

        const _Float16* BH = &Bbuf[buf][0][0][0];
        const _Float16* BL = &Bbuf[buf][1][0][0];
        const int rb = cl * DIM;
        #pragma unroll
        for (int ks = 0; ks < 16; ++ks) {
            int g = (2 * ks) ^ sw;     // swizzled granule for (ks, h)
            half8 bh = *(const half8*)(BH + rb + g * 8);
            half8 bl = *(const half8*)(BL + rb + g * 8);
            acc = __builtin_amdgcn_mfma_f32_32x32x16_f16(ah[ks], bh, acc, 0, 0, 0);
            acc = __builtin_amdgcn_mfma_f32_32x32x16_f16(al[ks], bh, acc, 0, 0, 0);
            acc = __builtin_amdgcn_mfma_f32_32x32x16_f16(ah[ks], bl, acc, 0, 0, 0);
        }

        const int col = c * 32 + cl;
        #pragma unroll
        for (int e = 0; e < 16; ++e) {
            float v = sq - acc[e];
            if (v < best_val[e]) { best_val[e] = v; best_idx[e] = col; }
        }

        __syncthreads();   // stage(c+1) landed; all readers of buf done
        buf ^= 1;
    }

    // ---- cross-lane argmin over the 32 code-columns (per accumulator row) ----
    #pragma unroll
    for (int e = 0; e < 16; ++e) {
        float v = best_val[e]; int ix = best_idx[e];
        #pragma unroll
        for (int off = 1; off < 32; off <<= 1) {
            float ov = __shfl_xor(v, off);
            int   oi = __shfl_xor(ix, off);
            if (ov < v || (ov == v && oi < ix)) { v = ov; ix = oi; }
        }
        best_val[e] = v; best_idx[e] = ix;
    }

    // rows of half h: r = (e&3) + 8*(e>>2) + 4*h — lanes 0 and 32 publish
    if (cl == 0) {
        #pragma unroll
        for (int e = 0; e < 16; ++e) {
            int r = (e & 3) + 8 * (e >> 2) + 4 * h;
            int grow = row0 + r;
            int j = best_idx[e];
            out[OFF_IND + grow] = (float)j;
            jint[grow] = j;
            atomicAdd(&counts[j], 1);
        }
    }

    // ---- winning code for THIS lane's row (row = cl): select chain + shfl ----
    int hr  = (cl >> 2) & 1;
    int reg = (cl & 3) + 4 * (cl >> 3);
    int cand = best_idx[0];
    #pragma unroll
    for (int e = 1; e < 16; ++e) cand = (reg == e) ? best_idx[e] : cand;
    int jm = __shfl(cand, hr * 32 + cl);

    // ---- quantize gather/write + diff partial (x rebuilt from ah+al) ----
    float dsum = 0.f;
    const float* qrow = embT + (size_t)jm * DIM + h * 8;
    float* qout = out + OFF_Q + (size_t)myrow * DIM + h * 8;
    #pragma unroll
    for (int ks = 0; ks < 16; ++ks) {
        f32x4 q0 = *(const f32x4*)(qrow + ks * 16);
        f32x4 q1 = *(const f32x4*)(qrow + ks * 16 + 4);
        *(f32x4*)(qout + ks * 16) = q0;
        *(f32x4*)(qout + ks * 16 + 4) = q1;
        #pragma unroll
        for (int i = 0; i < 4; ++i) {
            float x0 = (float)ah[ks][i] + (float)al[ks][i];
            float x1 = (float)ah[ks][4 + i] + (float)al[ks][4 + i];
            float d0 = q0[i] - x0, d1 = q1[i] - x1;
            dsum += d0 * d0 + d1 * d1;
        }
    }
    for (int off = 32; off; off >>= 1) dsum += __shfl_down(dsum, off);
    if (l == 0) dred[w] = dsum;
    __syncthreads();
    if (tid == 0) diffpart[blockIdx.x] = dred[0] + dred[1] + dred[2] + dred[3];
}

// ---------------- K2: scan + EMA scalars + diff finalize (1 block, 1024 thr) ----------------
__global__ void k2_small(const float* __restrict__ cluster_size,
                         const int* __restrict__ counts,
                         const float* __restrict__ diffpart,
                         float* __restrict__ out,
                         int* __restrict__ offsets,
                         float* __restrict__ cs_ws) {
    __shared__ float sf[1024];
    __shared__ int   si[1024];
    int t = threadIdx.x;
    int cnt = counts[t];
    float ncs = cluster_size[t] * DECAY + ONE_MINUS * (float)cnt;
    out[OFF_NCS + t] = ncs;

    sf[t] = ncs; __syncthreads();
    for (int s = 512; s; s >>= 1) { if (t < s) sf[t] += sf[t + s]; __syncthreads(); }
    float n = sf[0];
    float csv = (ncs + EPS) / (n + (float)NE * EPS) * n;
    cs_ws[t] = csv;

    si[t] = cnt; __syncthreads();
    for (int off = 1; off < 1024; off <<= 1) {
        int v = (t >= off) ? si[t - off] : 0;
        __syncthreads();
        si[t] += v;
        __syncthreads();
    }
    offsets[t] = si[t] - cnt;  // exclusive prefix

    float dp = diffpart[t];
    __syncthreads();
    sf[t] = dp; __syncthreads();
    for (int s = 512; s; s >>= 1) { if (t < s) sf[t] += sf[t + s]; __syncthreads(); }
    if (t == 0) out[OFF_DIFF] = sf[0] / 33554432.0f;
}

// ---------------- K3: scatter row ids into per-code buckets ----------------
__global__ void k3_scatter(const int* __restrict__ jint,
                           const int* __restrict__ offsets,
                           int* __restrict__ cursors,
                           int* __restrict__ list) {
    int r = blockIdx.x * 256 + threadIdx.x;
    int j = jint[r];
    int pos = atomicAdd(&cursors[j], 1);
    list[offsets[j] + pos] = r;
}

// ---------------- K4: per-code segment sum + EMA outputs ----------------
// 4-way row-parallel: wave w sums rows w, w+4, ...; lane l covers dims [4l,4l+4)
__global__ void k4_final(const float* __restrict__ input,
                         const float* __restrict__ embed_avg,
                         const int* __restrict__ counts,
                         const int* __restrict__ offsets,
                         const int* __restrict__ list,
                         const float* __restrict__ cs_ws,
                         float* __restrict__ out) {
    __shared__ float psum[4][256];
    __shared__ int lrows[1024];
    int j = blockIdx.x;
    int t = threadIdx.x;
    int w = t >> 6, l = t & 63;
    int cnt = counts[j], off = offsets[j];
    f32x4 s = {0.f, 0.f, 0.f, 0.f};
    for (int base = 0; base < cnt; base += 1024) {
        int m = min(cnt - base, 1024);
        __syncthreads();
        for (int i = t; i < m; i += 256) lrows[i] = list[off + base + i];
        __syncthreads();
        for (int i = w; i < m; i += 4) {
            f32x4 v = *(const f32x4*)(input + (size_t)lrows[i] * DIM + l * 4);
            s += v;
        }
    }
    __syncthreads();
    *(f32x4*)&psum[w][l * 4] = s;
    __syncthreads();
    int d = t;  // 0..255
    float tot = psum[0][d] + psum[1][d] + psum[2][d] + psum[3][d];
    float na = embed_avg[(size_t)d * NE + j] * DECAY + ONE_MINUS * tot;
    out[OFF_NEA + (size_t)d * NE + j] = na;
    out[OFF_NEMB + (size_t)d * NE + j] = na / cs_ws[j];
}

extern "C" void kernel_launch(void* const* d_in, const int* in_sizes, int n_in,
                              void* d_out, int out_size, void* d_ws, size_t ws_size,
                              hipStream_t stream) {
    const float* input        = (const float*)d_in[0];
    const float* embed        = (const float*)d_in[1];
    const float* cluster_size = (const float*)d_in[2];
    const float* embed_avg    = (const float*)d_in[3];
    float* out = (float*)d_out;
    char* ws = (char*)d_ws;

    _Float16* bt_hi  = (_Float16*)(ws + 0);
    _Float16* bt_lo  = (_Float16*)(ws + 524288);
    float*    embT   = (float*)(ws + 1048576);
    float*    sqh    = (float*)(ws + 2097152);
    int*      counts = (int*)(ws + 2101248);
    int*      offsets= (int*)(ws + 2105344);
    int*      cursors= (int*)(ws + 2113536);
    int*      jint   = (int*)(ws + 2117632);
    int*      list   = (int*)(ws + 2641920);
    float*    diffpart = (float*)(ws + 3166208);
    float*    cs_ws  = (float*)(ws + 3174400);

    hipMemsetAsync(counts, 0, 4096, stream);
    hipMemsetAsync(cursors, 0, 4096, stream);

    k0_prep<<<1024, 256, 0, stream>>>(embed, bt_hi, bt_lo, embT, sqh);
    k1_main<<<1024, 256, 0, stream>>>(input, bt_hi, bt_lo, embT, sqh, out, jint, counts, diffpart);
    k2_small<<<1, 1024, 0, stream>>>(cluster_size, counts, diffpart, out, offsets, cs_ws);
    k3_scatter<<<512, 256, 0, stream>>>(jint, offsets, cursors, list);
    k4_final<<<1024, 256, 0, stream>>>(input, embed_avg, counts, offsets, list, cs_ws, out);
}

// Round 3
// 967.150 us; speedup vs baseline: 1.2934x; 1.2934x over previous
//
#include <hip/hip_runtime.h>

typedef _Float16 half8 __attribute__((ext_vector_type(8)));
typedef float f32x4 __attribute__((ext_vector_type(4)));
typedef float f32x16 __attribute__((ext_vector_type(16)));

#define DIM 256
#define NE 1024
#define NROWS 131072
#define DECAY 0.99f
#define ONE_MINUS 0.01f
#define EPS 1e-5f

// output offsets (floats) in d_out, concatenated in reference return order
#define OFF_Q    0u
#define OFF_DIFF 33554432u
#define OFF_IND  33554433u
#define OFF_NEMB 33685505u
#define OFF_NCS  33947649u
#define OFF_NEA  33948673u

#define GLOAD16(gp, lp) __builtin_amdgcn_global_load_lds( \
    (__attribute__((address_space(1))) const void*)(gp),  \
    (__attribute__((address_space(3))) void*)(lp), 16, 0, 0)

// ---------------- K0: codebook transpose (LDS-tiled, coalesced both sides) ----
// embed [256][1024] -> bt_hi/bt_lo [1024][256] f16 planes + embT [1024][256] f32
__global__ void k0_prep(const float* __restrict__ embed,
                        _Float16* __restrict__ bt_hi, _Float16* __restrict__ bt_lo,
                        float* __restrict__ embT) {
    __shared__ float T[64][65];
    int t = threadIdx.x;
    int j0 = blockIdx.x * 64, d0 = blockIdx.y * 64;
    #pragma unroll
    for (int p = 0; p < 16; ++p) {
        int dd = p * 4 + (t >> 6), jj = t & 63;
        T[jj][dd] = embed[(size_t)(d0 + dd) * NE + j0 + jj];
    }
    __syncthreads();
    #pragma unroll
    for (int p = 0; p < 16; ++p) {
        int jj = p * 4 + (t >> 6), dd = t & 63;
        float e = T[jj][dd];
        int j = j0 + jj, d = d0 + dd;
        embT[(size_t)j * DIM + d] = e;
        _Float16 h = (_Float16)e;
        bt_hi[(size_t)j * DIM + d] = h;
        bt_lo[(size_t)j * DIM + d] = (_Float16)(e - (float)h);
    }
}

// ---------------- K0b: sqh[j] = 0.5*||e_j||^2 (deterministic, coalesced) ----
__global__ void k0b_sq(const float* __restrict__ embT, float* __restrict__ sqh) {
    int w = threadIdx.x >> 6, l = threadIdx.x & 63;
    int j = blockIdx.x * 4 + w;
    f32x4 v = *(const f32x4*)(embT + (size_t)j * DIM + l * 4);
    float s = v[0] * v[0] + v[1] * v[1] + v[2] * v[2] + v[3] * v[3];
    for (int off = 32; off; off >>= 1) s += __shfl_down(s, off);
    if (l == 0) sqh[j] = 0.5f * s;
}

// ---------------- K1: distance GEMM (32x32x16) + argmin + quantize + diff + hist ----
// 256 threads = 4 waves; wave owns 32 rows (A hi/lo fully register-resident);
// chunk = 32 codes staged hi+lo in LDS, double-buffered via global_load_lds
// with pre-swizzled source (LDS granule g' holds global granule g'^(row&7)).
__launch_bounds__(256, 2)
__global__ void k1_main(const float* __restrict__ input,
                        const _Float16* __restrict__ bt_hi,
                        const _Float16* __restrict__ bt_lo,
                        const float* __restrict__ embT,
                        const float* __restrict__ sqh,
                        float* __restrict__ out,
                        int* __restrict__ jint,
                        int* __restrict__ counts,
                        float* __restrict__ diffpart) {
    __shared__ _Float16 Bbuf[2][2][32][256];   // [buf][plane][row][half]  64 KB
    __shared__ float dred[4];

    const int tid = threadIdx.x;
    const int w  = tid >> 6;       // wave 0..3
    const int l  = tid & 63;       // lane
    const int cl = l & 31;         // code column / A row within wave tile
    const int h  = l >> 5;         // k-half
    const int sw = (l & 7) ^ h;    // read-swizzle term
    const int row0 = blockIdx.x * 128 + w * 32;
    const int myrow = row0 + cl;

    // ---- stage chunk 0 (async, in flight during A prep) ----
    #pragma unroll
    for (int i = 0; i < 8; ++i) {
        int q = i * 4 + w;          // 0..31 (wave-uniform)
        int plane = q >> 4;
        int p = q & 15;
        int G = p * 64 + l;
        int r = G >> 5;             // row 0..31
        int g = (G & 31) ^ (r & 7); // source granule (inverse swizzle)
        const _Float16* src = (plane ? bt_lo : bt_hi) + (size_t)r * DIM + g * 8;
        GLOAD16(src, &Bbuf[0][plane][p * 2][0]);
    }

    // ---- A load: one row per lane-pair, FULLY unrolled (all compile-time idx,
    //      rule #20: runtime-indexed ext_vector arrays go to scratch) ----
    half8 ah[16], al[16];
    {
        const float* arow = input + (size_t)myrow * DIM + h * 8;
        #pragma unroll
        for (int ks = 0; ks < 16; ++ks) {
            f32x4 x0 = *(const f32x4*)(arow + ks * 16);
            f32x4 x1 = *(const f32x4*)(arow + ks * 16 + 4);
            half8 hh, ll;
            #pragma unroll
            for (int i = 0; i < 4; ++i) {
                _Float16 h0 = (_Float16)x0[i];
                hh[i] = h0; ll[i] = (_Float16)(x0[i] - (float)h0);
                _Float16 h1 = (_Float16)x1[i];
                hh[4 + i] = h1; ll[4 + i] = (_Float16)(x1[i] - (float)h1);
            }
            ah[ks] = hh; al[ks] = ll;
        }
    }

    float best_val[16];
    int   best_idx[16];
    #pragma unroll
    for (int e = 0; e < 16; ++e) { best_val[e] = 3.4e38f; best_idx[e] = 0; }

    __syncthreads();   // drains vmcnt: chunk-0 stage + A loads complete

    int buf = 0;
    #pragma unroll 1
    for (int c = 0; c < 32; ++c) {
        // stage next chunk into the other buffer (latency hidden under MFMA)
        if (c < 31) {
            const int n0n = (c + 1) * 32;
            #pragma unroll
            for (int i = 0; i < 8; ++i) {
                int q = i * 4 + w;
                int plane = q >> 4;
                int p = q & 15;
                int G = p * 64 + l;
                int r = G >> 5;
                int g = (G & 31) ^ (r & 7);
                const _Float16* src = (plane ? bt_lo : bt_hi) + (size_t)(n0n + r) * DIM + g * 8;
                GLOAD16(src, &Bbuf[buf ^ 1][plane][p * 2][0]);
            }
        }
        float sq = sqh[c * 32 + cl];

        // two independent accumulator chains (even/odd ks) for MFMA ILP
        f32x16 acc0, acc1;
        #pragma unroll
        for (int e = 0; e < 16; ++e) { acc0[e] = 0.f; acc1[e] = 0.f; }

        const _Float16* BH = &Bbuf[buf][0][0][0];
        const _Float16* BL = &Bbuf[buf][1][0][0];
        const int rb = cl * DIM;
        #pragma unroll
        for (int ks = 0; ks < 16; ks += 2) {
            int g0 = (2 * ks) ^ sw;
            int g1 = (2 * (ks + 1)) ^ sw;
            half8 bh0 = *(const half8*)(BH + rb + g0 * 8);
            half8 bl0 = *(const half8*)(BL + rb + g0 * 8);
            half8 bh1 = *(const half8*)(BH + rb + g1 * 8);
            half8 bl1 = *(const half8*)(BL + rb + g1 * 8);
            acc0 = __builtin_amdgcn_mfma_f32_32x32x16_f16(ah[ks], bh0, acc0, 0, 0, 0);
            acc1 = __builtin_amdgcn_mfma_f32_32x32x16_f16(ah[ks + 1], bh1, acc1, 0, 0, 0);
            acc0 = __builtin_amdgcn_mfma_f32_32x32x16_f16(al[ks], bh0, acc0, 0, 0, 0);
            acc1 = __builtin_amdgcn_mfma_f32_32x32x16_f16(al[ks + 1], bh1, acc1, 0, 0, 0);
            acc0 = __builtin_amdgcn_mfma_f32_32x32x16_f16(ah[ks], bl0, acc0, 0, 0, 0);
            acc1 = __builtin_amdgcn_mfma_f32_32x32x16_f16(ah[ks + 1], bl1, acc1, 0, 0, 0);
        }

        const int col = c * 32 + cl;
        #pragma unroll
        for (int e = 0; e < 16; ++e) {
            float v = sq - (acc0[e] + acc1[e]);
            if (v < best_val[e]) { best_val[e] = v; best_idx[e] = col; }
        }

        __syncthreads();   // stage(c+1) landed; all readers of buf done
        buf ^= 1;
    }

    // ---- cross-lane argmin over the 32 code-columns (per accumulator reg) ----
    #pragma unroll
    for (int e = 0; e < 16; ++e) {
        float v = best_val[e]; int ix = best_idx[e];
        #pragma unroll
        for (int off = 1; off < 32; off <<= 1) {
            float ov = __shfl_xor(v, off);
            int   oi = __shfl_xor(ix, off);
            if (ov < v || (ov == v && oi < ix)) { v = ov; ix = oi; }
        }
        best_val[e] = v; best_idx[e] = ix;
    }

    // rows of half h: r = (e&3) + 8*(e>>2) + 4*h — lanes 0 and 32 publish
    if (cl == 0) {
        #pragma unroll
        for (int e = 0; e < 16; ++e) {
            int r = (e & 3) + 8 * (e >> 2) + 4 * h;
            int grow = row0 + r;
            int j = best_idx[e];
            out[OFF_IND + grow] = (float)j;
            jint[grow] = j;
            atomicAdd(&counts[j], 1);
        }
    }

    // ---- winning code for THIS lane's row (row = cl) ----
    int hr  = (cl >> 2) & 1;
    int reg = (cl & 3) + 4 * (cl >> 3);
    int cand = best_idx[0];
    #pragma unroll
    for (int e = 1; e < 16; ++e) cand = (reg == e) ? best_idx[e] : cand;
    int jm = __shfl(cand, hr * 32 + cl);

    // ---- quantize gather/write + diff partial (x rebuilt from ah+al) ----
    float dsum = 0.f;
    const float* qrow = embT + (size_t)jm * DIM + h * 8;
    float* qout = out + OFF_Q + (size_t)myrow * DIM + h * 8;
    #pragma unroll
    for (int ks = 0; ks < 16; ++ks) {
        f32x4 q0 = *(const f32x4*)(qrow + ks * 16);
        f32x4 q1 = *(const f32x4*)(qrow + ks * 16 + 4);
        *(f32x4*)(qout + ks * 16) = q0;
        *(f32x4*)(qout + ks * 16 + 4) = q1;
        #pragma unroll
        for (int i = 0; i < 4; ++i) {
            float x0 = (float)ah[ks][i] + (float)al[ks][i];
            float x1 = (float)ah[ks][4 + i] + (float)al[ks][4 + i];
            float d0 = q0[i] - x0, d1 = q1[i] - x1;
            dsum += d0 * d0 + d1 * d1;
        }
    }
    for (int off = 32; off; off >>= 1) dsum += __shfl_down(dsum, off);
    if (l == 0) dred[w] = dsum;
    __syncthreads();
    if (tid == 0) diffpart[blockIdx.x] = dred[0] + dred[1] + dred[2] + dred[3];
}

// ---------------- K2: scan + EMA scalars + diff finalize (1 block, 1024 thr) ----
__global__ void k2_small(const float* __restrict__ cluster_size,
                         const int* __restrict__ counts,
                         const float* __restrict__ diffpart,
                         float* __restrict__ out,
                         int* __restrict__ offsets,
                         float* __restrict__ cs_ws) {
    __shared__ float sf[1024];
    __shared__ int   si[1024];
    int t = threadIdx.x;
    int cnt = counts[t];
    float ncs = cluster_size[t] * DECAY + ONE_MINUS * (float)cnt;
    out[OFF_NCS + t] = ncs;

    sf[t] = ncs; __syncthreads();
    for (int s = 512; s; s >>= 1) { if (t < s) sf[t] += sf[t + s]; __syncthreads(); }
    float n = sf[0];
    float csv = (ncs + EPS) / (n + (float)NE * EPS) * n;
    cs_ws[t] = csv;

    si[t] = cnt; __syncthreads();
    for (int off = 1; off < 1024; off <<= 1) {
        int v = (t >= off) ? si[t - off] : 0;
        __syncthreads();
        si[t] += v;
        __syncthreads();
    }
    offsets[t] = si[t] - cnt;  // exclusive prefix

    float dp = diffpart[t];
    __syncthreads();
    sf[t] = dp; __syncthreads();
    for (int s = 512; s; s >>= 1) { if (t < s) sf[t] += sf[t + s]; __syncthreads(); }
    if (t == 0) out[OFF_DIFF] = sf[0] / 33554432.0f;
}

// ---------------- K3: scatter row ids into per-code buckets ----------------
__global__ void k3_scatter(const int* __restrict__ jint,
                           const int* __restrict__ offsets,
                           int* __restrict__ cursors,
                           int* __restrict__ list) {
    int r = blockIdx.x * 256 + threadIdx.x;
    int j = jint[r];
    int pos = atomicAdd(&cursors[j], 1);
    list[offsets[j] + pos] = r;
}

// ---------------- K4: per-code segment sum -> embed_sum[j][256] (contiguous) ----
__global__ void k4_segsum(const float* __restrict__ input,
                          const int* __restrict__ counts,
                          const int* __restrict__ offsets,
                          const int* __restrict__ list,
                          float* __restrict__ embed_sum) {
    __shared__ float psum[4][256];
    __shared__ int lrows[1024];
    int j = blockIdx.x;
    int t = threadIdx.x;
    int w = t >> 6, l = t & 63;
    int cnt = counts[j], off = offsets[j];
    f32x4 s = {0.f, 0.f, 0.f, 0.f};
    for (int base = 0; base < cnt; base += 1024) {
        int m = min(cnt - base, 1024);
        __syncthreads();
        for (int i = t; i < m; i += 256) lrows[i] = list[off + base + i];
        __syncthreads();
        for (int i = w; i < m; i += 4) {
            f32x4 v = *(const f32x4*)(input + (size_t)lrows[i] * DIM + l * 4);
            s += v;
        }
    }
    __syncthreads();
    *(f32x4*)&psum[w][l * 4] = s;
    __syncthreads();
    int d = t;  // 0..255
    embed_sum[(size_t)j * DIM + d] = psum[0][d] + psum[1][d] + psum[2][d] + psum[3][d];
}

// ---------------- K5: transpose + EMA outputs (LDS-tiled, coalesced) ----------
__global__ void k5_ema(const float* __restrict__ embed_sum,
                       const float* __restrict__ embed_avg,
                       const float* __restrict__ cs_ws,
                       float* __restrict__ out) {
    __shared__ float T[64][65];
    int t = threadIdx.x;
    int j0 = blockIdx.x * 64, d0 = blockIdx.y * 64;
    #pragma unroll
    for (int p = 0; p < 16; ++p) {
        int jj = p * 4 + (t >> 6), dd = t & 63;
        T[dd][jj] = embed_sum[(size_t)(j0 + jj) * DIM + d0 + dd];
    }
    __syncthreads();
    #pragma unroll
    for (int p = 0; p < 16; ++p) {
        int dd = p * 4 + (t >> 6), jj = t & 63;
        int d = d0 + dd, j = j0 + jj;
        float sum = T[dd][jj];
        float na = embed_avg[(size_t)d * NE + j] * DECAY + ONE_MINUS * sum;
        out[OFF_NEA + (size_t)d * NE + j] = na;
        out[OFF_NEMB + (size_t)d * NE + j] = na / cs_ws[j];
    }
}

extern "C" void kernel_launch(void* const* d_in, const int* in_sizes, int n_in,
                              void* d_out, int out_size, void* d_ws, size_t ws_size,
                              hipStream_t stream) {
    const float* input        = (const float*)d_in[0];
    const float* embed        = (const float*)d_in[1];
    const float* cluster_size = (const float*)d_in[2];
    const float* embed_avg    = (const float*)d_in[3];
    float* out = (float*)d_out;
    char* ws = (char*)d_ws;

    _Float16* bt_hi  = (_Float16*)(ws + 0);
    _Float16* bt_lo  = (_Float16*)(ws + 524288);
    float*    embT   = (float*)(ws + 1048576);
    float*    sqh    = (float*)(ws + 2097152);
    int*      counts = (int*)(ws + 2101248);
    int*      offsets= (int*)(ws + 2105344);
    int*      cursors= (int*)(ws + 2113536);
    int*      jint   = (int*)(ws + 2117632);
    int*      list   = (int*)(ws + 2641920);
    float*    diffpart = (float*)(ws + 3166208);
    float*    cs_ws  = (float*)(ws + 3174400);
    // k4/k5 run after k1 is done with the f16 planes: reuse that 1 MB region
    float*    embed_sum = (float*)(ws + 0);   // [1024][256] f32

    hipMemsetAsync(counts, 0, 4096, stream);
    hipMemsetAsync(cursors, 0, 4096, stream);

    k0_prep<<<dim3(16, 4), 256, 0, stream>>>(embed, bt_hi, bt_lo, embT);
    k0b_sq<<<256, 256, 0, stream>>>(embT, sqh);
    k1_main<<<1024, 256, 0, stream>>>(input, bt_hi, bt_lo, embT, sqh, out, jint, counts, diffpart);
    k2_small<<<1, 1024, 0, stream>>>(cluster_size, counts, diffpart, out, offsets, cs_ws);
    k3_scatter<<<512, 256, 0, stream>>>(jint, offsets, cursors, list);
    k4_segsum<<<1024, 256, 0, stream>>>(input, counts, offsets, list, embed_sum);
    k5_ema<<<dim3(16, 4), 256, 0, stream>>>(embed_sum, embed_avg, cs_ws, out);
}

// Round 4
// 522.177 us; speedup vs baseline: 2.3956x; 1.8521x over previous
//
#include <hip/hip_runtime.h>

typedef _Float16 half8 __attribute__((ext_vector_type(8)));
typedef float f32x4 __attribute__((ext_vector_type(4)));
typedef float f32x16 __attribute__((ext_vector_type(16)));

#define DIM 256
#define NE 1024
#define NROWS 131072
#define DECAY 0.99f
#define ONE_MINUS 0.01f
#define EPS 1e-5f

// output offsets (floats) in d_out, concatenated in reference return order
#define OFF_Q    0u
#define OFF_DIFF 33554432u
#define OFF_IND  33554433u
#define OFF_NEMB 33685505u
#define OFF_NCS  33947649u
#define OFF_NEA  33948673u

#define GLOAD16(gp, lp) __builtin_amdgcn_global_load_lds( \
    (__attribute__((address_space(1))) const void*)(gp),  \
    (__attribute__((address_space(3))) void*)(lp), 16, 0, 0)

// ---------------- K0: codebook transpose (LDS-tiled, coalesced both sides) ----
__global__ void k0_prep(const float* __restrict__ embed,
                        _Float16* __restrict__ bt_hi, _Float16* __restrict__ bt_lo,
                        float* __restrict__ embT) {
    __shared__ float T[64][65];
    int t = threadIdx.x;
    int j0 = blockIdx.x * 64, d0 = blockIdx.y * 64;
    #pragma unroll
    for (int p = 0; p < 16; ++p) {
        int dd = p * 4 + (t >> 6), jj = t & 63;
        T[jj][dd] = embed[(size_t)(d0 + dd) * NE + j0 + jj];
    }
    __syncthreads();
    #pragma unroll
    for (int p = 0; p < 16; ++p) {
        int jj = p * 4 + (t >> 6), dd = t & 63;
        float e = T[jj][dd];
        int j = j0 + jj, d = d0 + dd;
        embT[(size_t)j * DIM + d] = e;
        _Float16 h = (_Float16)e;
        bt_hi[(size_t)j * DIM + d] = h;
        bt_lo[(size_t)j * DIM + d] = (_Float16)(e - (float)h);
    }
}

// ---------------- K0b: sqh[j] = 0.5*||e_j||^2 ----------------
__global__ void k0b_sq(const float* __restrict__ embT, float* __restrict__ sqh) {
    int w = threadIdx.x >> 6, l = threadIdx.x & 63;
    int j = blockIdx.x * 4 + w;
    f32x4 v = *(const f32x4*)(embT + (size_t)j * DIM + l * 4);
    float s = v[0] * v[0] + v[1] * v[1] + v[2] * v[2] + v[3] * v[3];
    for (int off = 32; off; off >>= 1) s += __shfl_down(s, off);
    if (l == 0) sqh[j] = 0.5f * s;
}

// ---------------- K1: distance GEMM (32x32x16) + argmin + quantize + diff + hist ----
__launch_bounds__(256, 2)
__global__ void k1_main(const float* __restrict__ input,
                        const _Float16* __restrict__ bt_hi,
                        const _Float16* __restrict__ bt_lo,
                        const float* __restrict__ embT,
                        const float* __restrict__ sqh,
                        float* __restrict__ out,
                        int* __restrict__ jint,
                        int* __restrict__ counts,
                        float* __restrict__ diffpart) {
    __shared__ _Float16 Bbuf[2][2][32][256];   // [buf][plane][row][half]  64 KB
    __shared__ float dred[4];

    const int tid = threadIdx.x;
    const int w  = tid >> 6;
    const int l  = tid & 63;
    const int cl = l & 31;
    const int h  = l >> 5;
    const int sw = (l & 7) ^ h;
    const int row0 = blockIdx.x * 128 + w * 32;
    const int myrow = row0 + cl;

    #pragma unroll
    for (int i = 0; i < 8; ++i) {
        int q = i * 4 + w;
        int plane = q >> 4;
        int p = q & 15;
        int G = p * 64 + l;
        int r = G >> 5;
        int g = (G & 31) ^ (r & 7);
        const _Float16* src = (plane ? bt_lo : bt_hi) + (size_t)r * DIM + g * 8;
        GLOAD16(src, &Bbuf[0][plane][p * 2][0]);
    }

    half8 ah[16], al[16];
    {
        const float* arow = input + (size_t)myrow * DIM + h * 8;
        #pragma unroll
        for (int ks = 0; ks < 16; ++ks) {
            f32x4 x0 = *(const f32x4*)(arow + ks * 16);
            f32x4 x1 = *(const f32x4*)(arow + ks * 16 + 4);
            half8 hh, ll;
            #pragma unroll
            for (int i = 0; i < 4; ++i) {
                _Float16 h0 = (_Float16)x0[i];
                hh[i] = h0; ll[i] = (_Float16)(x0[i] - (float)h0);
                _Float16 h1 = (_Float16)x1[i];
                hh[4 + i] = h1; ll[4 + i] = (_Float16)(x1[i] - (float)h1);
            }
            ah[ks] = hh; al[ks] = ll;
        }
    }

    float best_val[16];
    int   best_idx[16];
    #pragma unroll
    for (int e = 0; e < 16; ++e) { best_val[e] = 3.4e38f; best_idx[e] = 0; }

    __syncthreads();

    int buf = 0;
    #pragma unroll 1
    for (int c = 0; c < 32; ++c) {
        if (c < 31) {
            const int n0n = (c + 1) * 32;
            #pragma unroll
            for (int i = 0; i < 8; ++i) {
                int q = i * 4 + w;
                int plane = q >> 4;
                int p = q & 15;
                int G = p * 64 + l;
                int r = G >> 5;
                int g = (G & 31) ^ (r & 7);
                const _Float16* src = (plane ? bt_lo : bt_hi) + (size_t)(n0n + r) * DIM + g * 8;
                GLOAD16(src, &Bbuf[buf ^ 1][plane][p * 2][0]);
            }
        }
        float sq = sqh[c * 32 + cl];

        f32x16 acc0, acc1;
        #pragma unroll
        for (int e = 0; e < 16; ++e) { acc0[e] = 0.f; acc1[e] = 0.f; }

        const _Float16* BH = &Bbuf[buf][0][0][0];
        const _Float16* BL = &Bbuf[buf][1][0][0];
        const int rb = cl * DIM;
        #pragma unroll
        for (int ks = 0; ks < 16; ks += 2) {
            int g0 = (2 * ks) ^ sw;
            int g1 = (2 * (ks + 1)) ^ sw;
            half8 bh0 = *(const half8*)(BH + rb + g0 * 8);
            half8 bl0 = *(const half8*)(BL + rb + g0 * 8);
            half8 bh1 = *(const half8*)(BH + rb + g1 * 8);
            half8 bl1 = *(const half8*)(BL + rb + g1 * 8);
            acc0 = __builtin_amdgcn_mfma_f32_32x32x16_f16(ah[ks], bh0, acc0, 0, 0, 0);
            acc1 = __builtin_amdgcn_mfma_f32_32x32x16_f16(ah[ks + 1], bh1, acc1, 0, 0, 0);
            acc0 = __builtin_amdgcn_mfma_f32_32x32x16_f16(al[ks], bh0, acc0, 0, 0, 0);
            acc1 = __builtin_amdgcn_mfma_f32_32x32x16_f16(al[ks + 1], bh1, acc1, 0, 0, 0);
            acc0 = __builtin_amdgcn_mfma_f32_32x32x16_f16(ah[ks], bl0, acc0, 0, 0, 0);
            acc1 = __builtin_amdgcn_mfma_f32_32x32x16_f16(ah[ks + 1], bl1, acc1, 0, 0, 0);
        }

        const int col = c * 32 + cl;
        #pragma unroll
        for (int e = 0; e < 16; ++e) {
            float v = sq - (acc0[e] + acc1[e]);
            if (v < best_val[e]) { best_val[e] = v; best_idx[e] = col; }
        }

        __syncthreads();
        buf ^= 1;
    }

    #pragma unroll
    for (int e = 0; e < 16; ++e) {
        float v = best_val[e]; int ix = best_idx[e];
        #pragma unroll
        for (int off = 1; off < 32; off <<= 1) {
            float ov = __shfl_xor(v, off);
            int   oi = __shfl_xor(ix, off);
            if (ov < v || (ov == v && oi < ix)) { v = ov; ix = oi; }
        }
        best_val[e] = v; best_idx[e] = ix;
    }

    if (cl == 0) {
        #pragma unroll
        for (int e = 0; e < 16; ++e) {
            int r = (e & 3) + 8 * (e >> 2) + 4 * h;
            int grow = row0 + r;
            int j = best_idx[e];
            out[OFF_IND + grow] = (float)j;
            jint[grow] = j;
            atomicAdd(&counts[j], 1);
        }
    }

    int hr  = (cl >> 2) & 1;
    int reg = (cl & 3) + 4 * (cl >> 3);
    int cand = best_idx[0];
    #pragma unroll
    for (int e = 1; e < 16; ++e) cand = (reg == e) ? best_idx[e] : cand;
    int jm = __shfl(cand, hr * 32 + cl);

    float dsum = 0.f;
    const float* qrow = embT + (size_t)jm * DIM + h * 8;
    float* qout = out + OFF_Q + (size_t)myrow * DIM + h * 8;
    #pragma unroll
    for (int ks = 0; ks < 16; ++ks) {
        f32x4 q0 = *(const f32x4*)(qrow + ks * 16);
        f32x4 q1 = *(const f32x4*)(qrow + ks * 16 + 4);
        *(f32x4*)(qout + ks * 16) = q0;
        *(f32x4*)(qout + ks * 16 + 4) = q1;
        #pragma unroll
        for (int i = 0; i < 4; ++i) {
            float x0 = (float)ah[ks][i] + (float)al[ks][i];
            float x1 = (float)ah[ks][4 + i] + (float)al[ks][4 + i];
            float d0 = q0[i] - x0, d1 = q1[i] - x1;
            dsum += d0 * d0 + d1 * d1;
        }
    }
    for (int off = 32; off; off >>= 1) dsum += __shfl_down(dsum, off);
    if (l == 0) dred[w] = dsum;
    __syncthreads();
    if (tid == 0) diffpart[blockIdx.x] = dred[0] + dred[1] + dred[2] + dred[3];
}

// ---------------- K2: shfl-scan + EMA scalars + diff finalize (1 block, 1024 thr) ----
__global__ void k2_small(const float* __restrict__ cluster_size,
                         const int* __restrict__ counts,
                         const float* __restrict__ diffpart,
                         float* __restrict__ out,
                         int* __restrict__ offsets,
                         float* __restrict__ cs_ws) {
    __shared__ int   wtot[16];
    __shared__ float wsum[16], wdiff[16];
    int t = threadIdx.x, w = t >> 6, l = t & 63;
    int cnt = counts[t];
    float ncs = cluster_size[t] * DECAY + ONE_MINUS * (float)cnt;
    out[OFF_NCS + t] = ncs;

    // wave-inclusive scan of cnt
    int sc = cnt;
    #pragma unroll
    for (int off = 1; off < 64; off <<= 1) {
        int v = __shfl_up(sc, off);
        if (l >= off) sc += v;
    }
    // wave sums of ncs and diffpart
    float ws = ncs;
    float dp = diffpart[t];
    #pragma unroll
    for (int off = 32; off; off >>= 1) {
        ws += __shfl_xor(ws, off);
        dp += __shfl_xor(dp, off);
    }
    if (l == 63) wtot[w] = sc;
    if (l == 0) { wsum[w] = ws; wdiff[w] = dp; }
    __syncthreads();
    int woff = 0; float n = 0.f, dtot = 0.f;
    #pragma unroll
    for (int i = 0; i < 16; ++i) {
        woff += (i < w) ? wtot[i] : 0;
        n += wsum[i];
        dtot += wdiff[i];
    }
    offsets[t] = woff + sc - cnt;       // exclusive prefix
    cs_ws[t] = (ncs + EPS) / (n + (float)NE * EPS) * n;
    if (t == 0) out[OFF_DIFF] = dtot / 33554432.0f;
}

// ---------------- K3: scatter row ids into per-code buckets ----------------
__global__ void k3_scatter(const int* __restrict__ jint,
                           const int* __restrict__ offsets,
                           int* __restrict__ cursors,
                           int* __restrict__ list) {
    int r = blockIdx.x * 256 + threadIdx.x;
    int j = jint[r];
    int pos = atomicAdd(&cursors[j], 1);
    list[offsets[j] + pos] = r;
}

// ---------------- K4: BALANCED segment sum over sorted list ----------------
// Each wave owns 32 consecutive list entries (uniform work); runs of equal
// code accumulate in registers; flush = 4 atomicAdds/lane into embed_sum[j].
#define K4FLUSH() do {                                                   \
    float* dst = embed_sum + (size_t)curj * DIM + l * 4;                 \
    atomicAdd(dst + 0, acc[0]); atomicAdd(dst + 1, acc[1]);              \
    atomicAdd(dst + 2, acc[2]); atomicAdd(dst + 3, acc[3]);              \
    acc[0] = acc[1] = acc[2] = acc[3] = 0.f;                             \
} while (0)

__global__ void k4_segsum(const float* __restrict__ input,
                          const int* __restrict__ jint,
                          const int* __restrict__ list,
                          float* __restrict__ embed_sum) {
    int wid = (blockIdx.x * 256 + threadIdx.x) >> 6;   // 0..4095
    int l = threadIdx.x & 63;
    int p0 = wid * 32;
    int row_l = list[p0 + (l & 31)];
    int j_l = jint[row_l];
    f32x4 acc = {0.f, 0.f, 0.f, 0.f};
    int curj = __shfl(j_l, 0);
    #pragma unroll 1
    for (int g = 0; g < 8; ++g) {
        int r0 = __shfl(row_l, 4 * g + 0), j0 = __shfl(j_l, 4 * g + 0);
        int r1 = __shfl(row_l, 4 * g + 1), j1 = __shfl(j_l, 4 * g + 1);
        int r2 = __shfl(row_l, 4 * g + 2), j2 = __shfl(j_l, 4 * g + 2);
        int r3 = __shfl(row_l, 4 * g + 3), j3 = __shfl(j_l, 4 * g + 3);
        f32x4 v0 = *(const f32x4*)(input + (size_t)r0 * DIM + l * 4);
        f32x4 v1 = *(const f32x4*)(input + (size_t)r1 * DIM + l * 4);
        f32x4 v2 = *(const f32x4*)(input + (size_t)r2 * DIM + l * 4);
        f32x4 v3 = *(const f32x4*)(input + (size_t)r3 * DIM + l * 4);
        if (j0 != curj) { K4FLUSH(); curj = j0; }
        acc += v0;
        if (j1 != curj) { K4FLUSH(); curj = j1; }
        acc += v1;
        if (j2 != curj) { K4FLUSH(); curj = j2; }
        acc += v2;
        if (j3 != curj) { K4FLUSH(); curj = j3; }
        acc += v3;
    }
    K4FLUSH();
}

// ---------------- K5: transpose + EMA outputs (LDS-tiled, coalesced) ----------
__global__ void k5_ema(const float* __restrict__ embed_sum,
                       const float* __restrict__ embed_avg,
                       const float* __restrict__ cs_ws,
                       float* __restrict__ out) {
    __shared__ float T[64][65];
    int t = threadIdx.x;
    int j0 = blockIdx.x * 64, d0 = blockIdx.y * 64;
    #pragma unroll
    for (int p = 0; p < 16; ++p) {
        int jj = p * 4 + (t >> 6), dd = t & 63;
        T[dd][jj] = embed_sum[(size_t)(j0 + jj) * DIM + d0 + dd];
    }
    __syncthreads();
    #pragma unroll
    for (int p = 0; p < 16; ++p) {
        int dd = p * 4 + (t >> 6), jj = t & 63;
        int d = d0 + dd, j = j0 + jj;
        float sum = T[dd][jj];
        float na = embed_avg[(size_t)d * NE + j] * DECAY + ONE_MINUS * sum;
        out[OFF_NEA + (size_t)d * NE + j] = na;
        out[OFF_NEMB + (size_t)d * NE + j] = na / cs_ws[j];
    }
}

extern "C" void kernel_launch(void* const* d_in, const int* in_sizes, int n_in,
                              void* d_out, int out_size, void* d_ws, size_t ws_size,
                              hipStream_t stream) {
    const float* input        = (const float*)d_in[0];
    const float* embed        = (const float*)d_in[1];
    const float* cluster_size = (const float*)d_in[2];
    const float* embed_avg    = (const float*)d_in[3];
    float* out = (float*)d_out;
    char* ws = (char*)d_ws;

    _Float16* bt_hi  = (_Float16*)(ws + 0);
    _Float16* bt_lo  = (_Float16*)(ws + 524288);
    float*    embT   = (float*)(ws + 1048576);
    float*    sqh    = (float*)(ws + 2097152);
    int*      counts = (int*)(ws + 2101248);
    int*      offsets= (int*)(ws + 2105344);
    int*      cursors= (int*)(ws + 2113536);
    int*      jint   = (int*)(ws + 2117632);
    int*      list   = (int*)(ws + 2641920);
    float*    diffpart = (float*)(ws + 3166208);
    float*    cs_ws  = (float*)(ws + 3174400);
    // k4/k5 run after k1 is done with the f16 planes: reuse that 1 MB region
    float*    embed_sum = (float*)(ws + 0);   // [1024][256] f32

    hipMemsetAsync(counts, 0, 4096, stream);
    hipMemsetAsync(cursors, 0, 4096, stream);

    k0_prep<<<dim3(16, 4), 256, 0, stream>>>(embed, bt_hi, bt_lo, embT);
    k0b_sq<<<256, 256, 0, stream>>>(embT, sqh);
    k1_main<<<1024, 256, 0, stream>>>(input, bt_hi, bt_lo, embT, sqh, out, jint, counts, diffpart);
    // bt_hi/bt_lo dead after k1 -> zero that region for embed_sum accumulation
    hipMemsetAsync(embed_sum, 0, (size_t)NE * DIM * sizeof(float), stream);
    k2_small<<<1, 1024, 0, stream>>>(cluster_size, counts, diffpart, out, offsets, cs_ws);
    k3_scatter<<<512, 256, 0, stream>>>(jint, offsets, cursors, list);
    k4_segsum<<<1024, 256, 0, stream>>>(input, jint, list, embed_sum);
    k5_ema<<<dim3(16, 4), 256, 0, stream>>>(embed_sum, embed_avg, cs_ws, out);
}

// Round 5
// 501.208 us; speedup vs baseline: 2.4959x; 1.0418x over previous
//
#include <hip/hip_runtime.h>

typedef _Float16 half8 __attribute__((ext_vector_type(8)));
typedef float f32x4 __attribute__((ext_vector_type(4)));
typedef float f32x16 __attribute__((ext_vector_type(16)));

#define DIM 256
#define NE 1024
#define NROWS 131072
#define DECAY 0.99f
#define ONE_MINUS 0.01f
#define EPS 1e-5f

// output offsets (floats) in d_out, concatenated in reference return order
#define OFF_Q    0u
#define OFF_DIFF 33554432u
#define OFF_IND  33554433u
#define OFF_NEMB 33685505u
#define OFF_NCS  33947649u
#define OFF_NEA  33948673u

#define GLOAD16(gp, lp) __builtin_amdgcn_global_load_lds( \
    (__attribute__((address_space(1))) const void*)(gp),  \
    (__attribute__((address_space(3))) void*)(lp), 16, 0, 0)

// ---------------- K0: codebook transpose (LDS-tiled, coalesced both sides) ----
__global__ void k0_prep(const float* __restrict__ embed,
                        _Float16* __restrict__ bt_hi, _Float16* __restrict__ bt_lo,
                        float* __restrict__ embT) {
    __shared__ float T[64][65];
    int t = threadIdx.x;
    int j0 = blockIdx.x * 64, d0 = blockIdx.y * 64;
    #pragma unroll
    for (int p = 0; p < 16; ++p) {
        int dd = p * 4 + (t >> 6), jj = t & 63;
        T[jj][dd] = embed[(size_t)(d0 + dd) * NE + j0 + jj];
    }
    __syncthreads();
    #pragma unroll
    for (int p = 0; p < 16; ++p) {
        int jj = p * 4 + (t >> 6), dd = t & 63;
        float e = T[jj][dd];
        int j = j0 + jj, d = d0 + dd;
        embT[(size_t)j * DIM + d] = e;
        _Float16 h = (_Float16)e;
        bt_hi[(size_t)j * DIM + d] = h;
        bt_lo[(size_t)j * DIM + d] = (_Float16)(e - (float)h);
    }
}

// ---------------- K0b: sqh[j] = 0.5*||e_j||^2 ----------------
__global__ void k0b_sq(const float* __restrict__ embT, float* __restrict__ sqh) {
    int w = threadIdx.x >> 6, l = threadIdx.x & 63;
    int j = blockIdx.x * 4 + w;
    f32x4 v = *(const f32x4*)(embT + (size_t)j * DIM + l * 4);
    float s = v[0] * v[0] + v[1] * v[1] + v[2] * v[2] + v[3] * v[3];
    for (int off = 32; off; off >>= 1) s += __shfl_down(s, off);
    if (l == 0) sqh[j] = 0.5f * s;
}

// ---------------- K1: distance GEMM (32x32x16) + argmin + quantize + diff + hist ----
// Counted-vmcnt pipeline (T3/T4): 2-deep chunk prefetch, vmcnt(8) waits (never 0
// in-loop), raw s_barrier (no full drain), setprio around MFMA cluster (T5).
__launch_bounds__(256, 2)
__global__ void k1_main(const float* __restrict__ input,
                        const _Float16* __restrict__ bt_hi,
                        const _Float16* __restrict__ bt_lo,
                        const float* __restrict__ embT,
                        const float* __restrict__ sqh,
                        float* __restrict__ out,
                        int* __restrict__ jint,
                        int* __restrict__ counts,
                        float* __restrict__ diffpart) {
    __shared__ _Float16 Bbuf[2][2][32][256];   // [buf][plane][row][half]  64 KB
    __shared__ float sq_lds[NE];               // 4 KB
    __shared__ float dred[4];

    const int tid = threadIdx.x;
    const int w  = tid >> 6;
    const int l  = tid & 63;
    const int cl = l & 31;
    const int h  = l >> 5;
    const int sw = (l & 7) ^ h;
    const int row0 = blockIdx.x * 128 + w * 32;
    const int myrow = row0 + cl;

    // stage chunk 0 -> buf0, chunk 1 -> buf1 (8 gload_lds each per wave)
    #pragma unroll
    for (int cc = 0; cc < 2; ++cc) {
        #pragma unroll
        for (int i = 0; i < 8; ++i) {
            int q = i * 4 + w;
            int plane = q >> 4;
            int p = q & 15;
            int G = p * 64 + l;
            int r = G >> 5;
            int g = (G & 31) ^ (r & 7);
            const _Float16* src = (plane ? bt_lo : bt_hi) + (size_t)(cc * 32 + r) * DIM + g * 8;
            GLOAD16(src, &Bbuf[cc][plane][p * 2][0]);
        }
    }

    // sqh -> LDS (keeps the main loop free of stray global loads for vmcnt counting)
    for (int i = tid; i < NE; i += 256) sq_lds[i] = sqh[i];

    // A load: one row per lane, fully unrolled (rule #20: static indices only)
    half8 ah[16], al[16];
    {
        const float* arow = input + (size_t)myrow * DIM + h * 8;
        #pragma unroll
        for (int ks = 0; ks < 16; ++ks) {
            f32x4 x0 = *(const f32x4*)(arow + ks * 16);
            f32x4 x1 = *(const f32x4*)(arow + ks * 16 + 4);
            half8 hh, ll;
            #pragma unroll
            for (int i = 0; i < 4; ++i) {
                _Float16 h0 = (_Float16)x0[i];
                hh[i] = h0; ll[i] = (_Float16)(x0[i] - (float)h0);
                _Float16 h1 = (_Float16)x1[i];
                hh[4 + i] = h1; ll[4 + i] = (_Float16)(x1[i] - (float)h1);
            }
            ah[ks] = hh; al[ks] = ll;
        }
    }

    float best_val[16];
    int   best_idx[16];
    #pragma unroll
    for (int e = 0; e < 16; ++e) { best_val[e] = 3.4e38f; best_idx[e] = 0; }

    __syncthreads();   // one-time full drain: chunks 0,1 + sq_lds visible

    int buf = 0;
    #pragma unroll 1
    for (int c = 0; c < 32; ++c) {
        // chunk c landed (own 8 oldest); chunk c+1 stays in flight
        if (c == 31) { asm volatile("s_waitcnt vmcnt(0)" ::: "memory"); }
        else         { asm volatile("s_waitcnt vmcnt(8)" ::: "memory"); }
        __builtin_amdgcn_s_barrier();

        f32x16 acc0, acc1;
        #pragma unroll
        for (int e = 0; e < 16; ++e) { acc0[e] = 0.f; acc1[e] = 0.f; }

        const _Float16* BH = &Bbuf[buf][0][0][0];
        const _Float16* BL = &Bbuf[buf][1][0][0];
        const int rb = cl * DIM;
        __builtin_amdgcn_s_setprio(1);
        #pragma unroll
        for (int ks = 0; ks < 16; ks += 2) {
            int g0 = (2 * ks) ^ sw;
            int g1 = (2 * (ks + 1)) ^ sw;
            half8 bh0 = *(const half8*)(BH + rb + g0 * 8);
            half8 bl0 = *(const half8*)(BL + rb + g0 * 8);
            half8 bh1 = *(const half8*)(BH + rb + g1 * 8);
            half8 bl1 = *(const half8*)(BL + rb + g1 * 8);
            acc0 = __builtin_amdgcn_mfma_f32_32x32x16_f16(ah[ks], bh0, acc0, 0, 0, 0);
            acc1 = __builtin_amdgcn_mfma_f32_32x32x16_f16(ah[ks + 1], bh1, acc1, 0, 0, 0);
            acc0 = __builtin_amdgcn_mfma_f32_32x32x16_f16(al[ks], bh0, acc0, 0, 0, 0);
            acc1 = __builtin_amdgcn_mfma_f32_32x32x16_f16(al[ks + 1], bh1, acc1, 0, 0, 0);
            acc0 = __builtin_amdgcn_mfma_f32_32x32x16_f16(ah[ks], bl0, acc0, 0, 0, 0);
            acc1 = __builtin_amdgcn_mfma_f32_32x32x16_f16(ah[ks + 1], bl1, acc1, 0, 0, 0);
        }
        __builtin_amdgcn_s_setprio(0);
        __builtin_amdgcn_s_barrier();   // all waves done reading Bbuf[buf]

        // stage chunk c+2 into the buffer just consumed (latency hides under
        // the next TWO iterations' compute)
        if (c < 30) {
            const int n0n = (c + 2) * 32;
            #pragma unroll
            for (int i = 0; i < 8; ++i) {
                int q = i * 4 + w;
                int plane = q >> 4;
                int p = q & 15;
                int G = p * 64 + l;
                int r = G >> 5;
                int g = (G & 31) ^ (r & 7);
                const _Float16* src = (plane ? bt_lo : bt_hi) + (size_t)(n0n + r) * DIM + g * 8;
                GLOAD16(src, &Bbuf[buf][plane][p * 2][0]);
            }
        }

        // register-only argmin update (placed after stage issue)
        float sq = sq_lds[c * 32 + cl];
        const int col = c * 32 + cl;
        #pragma unroll
        for (int e = 0; e < 16; ++e) {
            float v = sq - (acc0[e] + acc1[e]);
            if (v < best_val[e]) { best_val[e] = v; best_idx[e] = col; }
        }

        buf ^= 1;
    }

    #pragma unroll
    for (int e = 0; e < 16; ++e) {
        float v = best_val[e]; int ix = best_idx[e];
        #pragma unroll
        for (int off = 1; off < 32; off <<= 1) {
            float ov = __shfl_xor(v, off);
            int   oi = __shfl_xor(ix, off);
            if (ov < v || (ov == v && oi < ix)) { v = ov; ix = oi; }
        }
        best_val[e] = v; best_idx[e] = ix;
    }

    if (cl == 0) {
        #pragma unroll
        for (int e = 0; e < 16; ++e) {
            int r = (e & 3) + 8 * (e >> 2) + 4 * h;
            int grow = row0 + r;
            int j = best_idx[e];
            out[OFF_IND + grow] = (float)j;
            jint[grow] = j;
            atomicAdd(&counts[j], 1);
        }
    }

    int hr  = (cl >> 2) & 1;
    int reg = (cl & 3) + 4 * (cl >> 3);
    int cand = best_idx[0];
    #pragma unroll
    for (int e = 1; e < 16; ++e) cand = (reg == e) ? best_idx[e] : cand;
    int jm = __shfl(cand, hr * 32 + cl);

    float dsum = 0.f;
    const float* qrow = embT + (size_t)jm * DIM + h * 8;
    float* qout = out + OFF_Q + (size_t)myrow * DIM + h * 8;
    #pragma unroll
    for (int ks = 0; ks < 16; ++ks) {
        f32x4 q0 = *(const f32x4*)(qrow + ks * 16);
        f32x4 q1 = *(const f32x4*)(qrow + ks * 16 + 4);
        *(f32x4*)(qout + ks * 16) = q0;
        *(f32x4*)(qout + ks * 16 + 4) = q1;
        #pragma unroll
        for (int i = 0; i < 4; ++i) {
            float x0 = (float)ah[ks][i] + (float)al[ks][i];
            float x1 = (float)ah[ks][4 + i] + (float)al[ks][4 + i];
            float d0 = q0[i] - x0, d1 = q1[i] - x1;
            dsum += d0 * d0 + d1 * d1;
        }
    }
    for (int off = 32; off; off >>= 1) dsum += __shfl_down(dsum, off);
    if (l == 0) dred[w] = dsum;
    __syncthreads();
    if (tid == 0) diffpart[blockIdx.x] = dred[0] + dred[1] + dred[2] + dred[3];
}

// ---------------- K2: shfl-scan + EMA scalars + diff finalize (1 block, 1024 thr) ----
__global__ void k2_small(const float* __restrict__ cluster_size,
                         const int* __restrict__ counts,
                         const float* __restrict__ diffpart,
                         float* __restrict__ out,
                         int* __restrict__ offsets,
                         float* __restrict__ cs_ws) {
    __shared__ int   wtot[16];
    __shared__ float wsum[16], wdiff[16];
    int t = threadIdx.x, w = t >> 6, l = t & 63;
    int cnt = counts[t];
    float ncs = cluster_size[t] * DECAY + ONE_MINUS * (float)cnt;
    out[OFF_NCS + t] = ncs;

    int sc = cnt;
    #pragma unroll
    for (int off = 1; off < 64; off <<= 1) {
        int v = __shfl_up(sc, off);
        if (l >= off) sc += v;
    }
    float ws = ncs;
    float dp = diffpart[t];
    #pragma unroll
    for (int off = 32; off; off >>= 1) {
        ws += __shfl_xor(ws, off);
        dp += __shfl_xor(dp, off);
    }
    if (l == 63) wtot[w] = sc;
    if (l == 0) { wsum[w] = ws; wdiff[w] = dp; }
    __syncthreads();
    int woff = 0; float n = 0.f, dtot = 0.f;
    #pragma unroll
    for (int i = 0; i < 16; ++i) {
        woff += (i < w) ? wtot[i] : 0;
        n += wsum[i];
        dtot += wdiff[i];
    }
    offsets[t] = woff + sc - cnt;       // exclusive prefix
    cs_ws[t] = (ncs + EPS) / (n + (float)NE * EPS) * n;
    if (t == 0) out[OFF_DIFF] = dtot / 33554432.0f;
}

// ---------------- K3: scatter row ids into per-code buckets ----------------
__global__ void k3_scatter(const int* __restrict__ jint,
                           const int* __restrict__ offsets,
                           int* __restrict__ cursors,
                           int* __restrict__ list) {
    int r = blockIdx.x * 256 + threadIdx.x;
    int j = jint[r];
    int pos = atomicAdd(&cursors[j], 1);
    list[offsets[j] + pos] = r;
}

// ---------------- K4: BALANCED segment sum over sorted list ----------------
#define K4FLUSH() do {                                                   \
    float* dst = embed_sum + (size_t)curj * DIM + l * 4;                 \
    atomicAdd(dst + 0, acc[0]); atomicAdd(dst + 1, acc[1]);              \
    atomicAdd(dst + 2, acc[2]); atomicAdd(dst + 3, acc[3]);              \
    acc[0] = acc[1] = acc[2] = acc[3] = 0.f;                             \
} while (0)

__global__ void k4_segsum(const float* __restrict__ input,
                          const int* __restrict__ jint,
                          const int* __restrict__ list,
                          float* __restrict__ embed_sum) {
    int wid = (blockIdx.x * 256 + threadIdx.x) >> 6;   // 0..4095
    int l = threadIdx.x & 63;
    int p0 = wid * 32;
    int row_l = list[p0 + (l & 31)];
    int j_l = jint[row_l];
    f32x4 acc = {0.f, 0.f, 0.f, 0.f};
    int curj = __shfl(j_l, 0);
    #pragma unroll 1
    for (int g = 0; g < 8; ++g) {
        int r0 = __shfl(row_l, 4 * g + 0), j0 = __shfl(j_l, 4 * g + 0);
        int r1 = __shfl(row_l, 4 * g + 1), j1 = __shfl(j_l, 4 * g + 1);
        int r2 = __shfl(row_l, 4 * g + 2), j2 = __shfl(j_l, 4 * g + 2);
        int r3 = __shfl(row_l, 4 * g + 3), j3 = __shfl(j_l, 4 * g + 3);
        f32x4 v0 = *(const f32x4*)(input + (size_t)r0 * DIM + l * 4);
        f32x4 v1 = *(const f32x4*)(input + (size_t)r1 * DIM + l * 4);
        f32x4 v2 = *(const f32x4*)(input + (size_t)r2 * DIM + l * 4);
        f32x4 v3 = *(const f32x4*)(input + (size_t)r3 * DIM + l * 4);
        if (j0 != curj) { K4FLUSH(); curj = j0; }
        acc += v0;
        if (j1 != curj) { K4FLUSH(); curj = j1; }
        acc += v1;
        if (j2 != curj) { K4FLUSH(); curj = j2; }
        acc += v2;
        if (j3 != curj) { K4FLUSH(); curj = j3; }
        acc += v3;
    }
    K4FLUSH();
}

// ---------------- K5: transpose + EMA outputs (LDS-tiled, coalesced) ----------
__global__ void k5_ema(const float* __restrict__ embed_sum,
                       const float* __restrict__ embed_avg,
                       const float* __restrict__ cs_ws,
                       float* __restrict__ out) {
    __shared__ float T[64][65];
    int t = threadIdx.x;
    int j0 = blockIdx.x * 64, d0 = blockIdx.y * 64;
    #pragma unroll
    for (int p = 0; p < 16; ++p) {
        int jj = p * 4 + (t >> 6), dd = t & 63;
        T[dd][jj] = embed_sum[(size_t)(j0 + jj) * DIM + d0 + dd];
    }
    __syncthreads();
    #pragma unroll
    for (int p = 0; p < 16; ++p) {
        int dd = p * 4 + (t >> 6), jj = t & 63;
        int d = d0 + dd, j = j0 + jj;
        float sum = T[dd][jj];
        float na = embed_avg[(size_t)d * NE + j] * DECAY + ONE_MINUS * sum;
        out[OFF_NEA + (size_t)d * NE + j] = na;
        out[OFF_NEMB + (size_t)d * NE + j] = na / cs_ws[j];
    }
}

extern "C" void kernel_launch(void* const* d_in, const int* in_sizes, int n_in,
                              void* d_out, int out_size, void* d_ws, size_t ws_size,
                              hipStream_t stream) {
    const float* input        = (const float*)d_in[0];
    const float* embed        = (const float*)d_in[1];
    const float* cluster_size = (const float*)d_in[2];
    const float* embed_avg    = (const float*)d_in[3];
    float* out = (float*)d_out;
    char* ws = (char*)d_ws;

    _Float16* bt_hi  = (_Float16*)(ws + 0);
    _Float16* bt_lo  = (_Float16*)(ws + 524288);
    float*    embT   = (float*)(ws + 1048576);
    float*    sqh    = (float*)(ws + 2097152);
    int*      counts = (int*)(ws + 2101248);
    int*      offsets= (int*)(ws + 2105344);
    int*      cursors= (int*)(ws + 2113536);
    int*      jint   = (int*)(ws + 2117632);
    int*      list   = (int*)(ws + 2641920);
    float*    diffpart = (float*)(ws + 3166208);
    float*    cs_ws  = (float*)(ws + 3174400);
    // k4/k5 run after k1 is done with the f16 planes: reuse that 1 MB region
    float*    embed_sum = (float*)(ws + 0);   // [1024][256] f32

    hipMemsetAsync(counts, 0, 4096, stream);
    hipMemsetAsync(cursors, 0, 4096, stream);

    k0_prep<<<dim3(16, 4), 256, 0, stream>>>(embed, bt_hi, bt_lo, embT);
    k0b_sq<<<256, 256, 0, stream>>>(embT, sqh);
    k1_main<<<1024, 256, 0, stream>>>(input, bt_hi, bt_lo, embT, sqh, out, jint, counts, diffpart);
    // bt_hi/bt_lo dead after k1 -> zero that region for embed_sum accumulation
    hipMemsetAsync(embed_sum, 0, (size_t)NE * DIM * sizeof(float), stream);
    k2_small<<<1, 1024, 0, stream>>>(cluster_size, counts, diffpart, out, offsets, cs_ws);
    k3_scatter<<<512, 256, 0, stream>>>(jint, offsets, cursors, list);
    k4_segsum<<<1024, 256, 0, stream>>>(input, jint, list, embed_sum);
    k5_ema<<<dim3(16, 4), 256, 0, stream>>>(embed_sum, embed_avg, cs_ws, out);
}